// Round 4
// baseline (676.466 us; speedup 1.0000x reference)
//
#include <hip/hip_runtime.h>
#include <cstdint>
#include <cstddef>

#define B_N 2048
#define M_N 768
#define E_N 16384
#define K_N 32
#define EPSF 1e-8f

typedef __attribute__((ext_vector_type(8))) short short8;
typedef __attribute__((ext_vector_type(4))) float floatx4;

__device__ inline unsigned short f2bf(float f) {
  unsigned int u = __float_as_uint(f);
  unsigned int r = (u + 0x7fffu + ((u >> 16) & 1u)) >> 16;
  return (unsigned short)r;
}
__device__ inline float bf2f(unsigned short h) {
  return __uint_as_float(((unsigned int)h) << 16);
}

// Load 8 f32 and split into (hi, lo) bf16 short8 pair. Identical arithmetic
// to the old split kernel, done in-register at GEMM staging time.
__device__ inline void cvt8(const float* __restrict__ p, short8& h8, short8& l8) {
  float4 v0 = *(const float4*)p;
  float4 v1 = *(const float4*)(p + 4);
  float f[8] = {v0.x, v0.y, v0.z, v0.w, v1.x, v1.y, v1.z, v1.w};
#pragma unroll
  for (int j = 0; j < 8; ++j) {
    unsigned short h = f2bf(f[j]);
    ((unsigned short*)&h8)[j] = h;
    ((unsigned short*)&l8)[j] = f2bf(f[j] - bf2f(h));
  }
}

// ---------------------------------------------------------------------------
// Fused decoder prep: float4 global loads AND float4 global stores.
// Transpose all three [M,E]->[E,M] + accumulate 5 per-column stats from the
// LDS tiles during the store phase. stats pre-zeroed. grid (E/32, M/32).
// ---------------------------------------------------------------------------
__global__ __launch_bounds__(256) void prep_dec_kernel(
    const float* __restrict__ dw, const float* __restrict__ d1,
    const float* __restrict__ d2,
    float* __restrict__ dT0, float* __restrict__ dT1,
    float* __restrict__ dT2, float* __restrict__ stats) {
  __shared__ float t0[32][36], t1[32][36], t2[32][36];
  int tid = threadIdx.x;
  int e0 = blockIdx.x * 32;
  int m0 = blockIdx.y * 32;

  {
    int ml = tid >> 3, e4 = tid & 7;
    size_t gbase = (size_t)(m0 + ml) * E_N + e0 + e4 * 4;
    float4 a  = *(const float4*)&dw[gbase];
    float4 b1 = *(const float4*)&d1[gbase];
    float4 b2 = *(const float4*)&d2[gbase];
    *(float4*)&t0[ml][e4 * 4] = a;
    *(float4*)&t1[ml][e4 * 4] = b1;
    *(float4*)&t2[ml][e4 * 4] = b2;
  }
  __syncthreads();

  int el = tid >> 3, m4 = tid & 7;
  float4 v0, v1, v2;
  float s0 = 0.f, s1 = 0.f, s2 = 0.f, s3 = 0.f, s4 = 0.f;
#pragma unroll
  for (int j = 0; j < 4; ++j) {
    float A  = t0[m4 * 4 + j][el];
    float B1 = t1[m4 * 4 + j][el];
    float B2 = t2[m4 * 4 + j][el];
    ((float*)&v0)[j] = A;
    ((float*)&v1)[j] = B1;
    ((float*)&v2)[j] = B2;
    s0 = fmaf(A, A, s0);
    s1 = fmaf(B1, B1, s1);
    s2 = fmaf(B2, B2, s2);
    s3 = fmaf(A, B1, s3);
    s4 = fmaf(A, B2, s4);
  }
  size_t tbase = (size_t)(e0 + el) * M_N + m0 + m4 * 4;
  *(float4*)&dT0[tbase] = v0;
  *(float4*)&dT1[tbase] = v1;
  *(float4*)&dT2[tbase] = v2;

#pragma unroll
  for (int off = 1; off < 8; off <<= 1) {
    s0 += __shfl_xor(s0, off);
    s1 += __shfl_xor(s1, off);
    s2 += __shfl_xor(s2, off);
    s3 += __shfl_xor(s3, off);
    s4 += __shfl_xor(s4, off);
  }
  if (m4 == 0) {
    int e = e0 + el;
    atomicAdd(&stats[e], s0);
    atomicAdd(&stats[E_N + e], s1);
    atomicAdd(&stats[2 * E_N + e], s2);
    atomicAdd(&stats[3 * E_N + e], s3);
    atomicAdd(&stats[4 * E_N + e], s4);
  }
}

// ---------------------------------------------------------------------------
// pre = x @ enc_w.T + enc_b via split-bf16 MFMA (hi*hi + hi*lo + lo*hi).
// v3: reads f32 A/B directly and converts to (hi,lo) at staging time —
// eliminates the separate split kernel (same HBM bytes: 2x bf16 == f32).
// ---------------------------------------------------------------------------
#define TM 128
#define TN 128
#define TK 32
#define LDK 40

__global__ __launch_bounds__(256) void gemm_mfma_kernel(
    const float* __restrict__ A, const float* __restrict__ Bm,
    const float* __restrict__ bias, float* __restrict__ C) {
  __shared__ __align__(16) unsigned short As_hi[TM * LDK];
  __shared__ __align__(16) unsigned short As_lo[TM * LDK];
  __shared__ __align__(16) unsigned short Bs_hi[TM * LDK];
  __shared__ __align__(16) unsigned short Bs_lo[TM * LDK];

  int tid = threadIdx.x;
  int lane = tid & 63;
  int wave = tid >> 6;
  int i0 = blockIdx.y * TM;
  int j0 = blockIdx.x * TN;
  int wm = (wave >> 1) * 64;
  int wn = (wave & 1) * 64;

  int row0 = tid >> 2, c40 = tid & 3;
  int row1 = 64 + (tid >> 2), c41 = tid & 3;
  const float* pA0 = A + (size_t)(i0 + row0) * M_N + c40 * 8;
  const float* pA1 = A + (size_t)(i0 + row1) * M_N + c41 * 8;
  const float* pB0 = Bm + (size_t)(j0 + row0) * M_N + c40 * 8;
  const float* pB1 = Bm + (size_t)(j0 + row1) * M_N + c41 * 8;
  int l0 = row0 * LDK + c40 * 8;
  int l1 = row1 * LDK + c41 * 8;

  floatx4 acc[4][4];
#pragma unroll
  for (int i = 0; i < 4; ++i)
#pragma unroll
    for (int j = 0; j < 4; ++j) acc[i][j] = (floatx4){0.f, 0.f, 0.f, 0.f};

  int fr = lane & 15;
  int fk = (lane >> 4) * 8;

  short8 vAh0, vAl0, vAh1, vAl1, vBh0, vBl0, vBh1, vBl1;
  cvt8(pA0, vAh0, vAl0);
  cvt8(pA1, vAh1, vAl1);
  cvt8(pB0, vBh0, vBl0);
  cvt8(pB1, vBh1, vBl1);

  for (int k0 = 0; k0 < M_N; k0 += TK) {
    __syncthreads();
    *(short8*)&As_hi[l0] = vAh0;
    *(short8*)&As_hi[l1] = vAh1;
    *(short8*)&As_lo[l0] = vAl0;
    *(short8*)&As_lo[l1] = vAl1;
    *(short8*)&Bs_hi[l0] = vBh0;
    *(short8*)&Bs_hi[l1] = vBh1;
    *(short8*)&Bs_lo[l0] = vBl0;
    *(short8*)&Bs_lo[l1] = vBl1;
    __syncthreads();

    if (k0 + TK < M_N) {
      int d = k0 + TK;
      cvt8(pA0 + d, vAh0, vAl0);
      cvt8(pA1 + d, vAh1, vAl1);
      cvt8(pB0 + d, vBh0, vBl0);
      cvt8(pB1 + d, vBh1, vBl1);
    }

    short8 ah[4], al[4], bh[4], bl[4];
#pragma unroll
    for (int t = 0; t < 4; ++t) {
      int ar = (wm + t * 16 + fr) * LDK + fk;
      int br = (wn + t * 16 + fr) * LDK + fk;
      ah[t] = *(const short8*)&As_hi[ar];
      al[t] = *(const short8*)&As_lo[ar];
      bh[t] = *(const short8*)&Bs_hi[br];
      bl[t] = *(const short8*)&Bs_lo[br];
    }
#pragma unroll
    for (int mi = 0; mi < 4; ++mi)
#pragma unroll
      for (int ni = 0; ni < 4; ++ni) {
        acc[mi][ni] = __builtin_amdgcn_mfma_f32_16x16x32_bf16(ah[mi], bh[ni], acc[mi][ni], 0, 0, 0);
        acc[mi][ni] = __builtin_amdgcn_mfma_f32_16x16x32_bf16(ah[mi], bl[ni], acc[mi][ni], 0, 0, 0);
        acc[mi][ni] = __builtin_amdgcn_mfma_f32_16x16x32_bf16(al[mi], bh[ni], acc[mi][ni], 0, 0, 0);
      }
  }

#pragma unroll
  for (int mi = 0; mi < 4; ++mi) {
    int rbase = i0 + wm + mi * 16 + (lane >> 4) * 4;
#pragma unroll
    for (int ni = 0; ni < 4; ++ni) {
      int col = j0 + wn + ni * 16 + (lane & 15);
      float bb = bias[col];
#pragma unroll
      for (int r = 0; r < 4; ++r) {
        C[(size_t)(rbase + r) * E_N + col] = acc[mi][ni][r] + bb;
      }
    }
  }
}

// ---------------------------------------------------------------------------
// Exact top-K per row via radix-select on the monotone u32 key.
// Matches jax.lax.top_k (ties -> lowest index).
// ---------------------------------------------------------------------------
__global__ __launch_bounds__(256) void topk_kernel(const float* __restrict__ pre,
                                                   int* __restrict__ topk_idx,
                                                   float* __restrict__ topk_val,
                                                   int* __restrict__ live_p) {
  int b = blockIdx.x;
  int tid = threadIdx.x;
  int wave = tid >> 6;
  const float* row = pre + (size_t)b * E_N;

  __shared__ __align__(16) unsigned int hist4[4][2048];  // 32 KB
  __shared__ unsigned int csum[256];
  __shared__ float candV[2048];
  __shared__ int candI[2048];
  __shared__ float defV[K_N];
  __shared__ int defI[K_N];
  __shared__ int s_T, s_nDef, s_nCand;

  uint4 z4 = make_uint4(0u, 0u, 0u, 0u);
  uint4* hz = (uint4*)&hist4[0][0];
  for (int i = tid; i < 2048; i += 256) hz[i] = z4;
  if (tid == 0) { s_nDef = 0; s_nCand = 0; }
  __syncthreads();

  // pass 1: per-wave histogram of top-11 key bits (float4 loads)
  for (int j = 0; j < E_N / 1024; ++j) {
    float4 v = ((const float4*)row)[tid + j * 256];
    float f[4] = {v.x, v.y, v.z, v.w};
#pragma unroll
    for (int q = 0; q < 4; ++q) {
      unsigned int u = __float_as_uint(f[q]);
      unsigned int key = (u & 0x80000000u) ? ~u : (u | 0x80000000u);
      atomicAdd(&hist4[wave][key >> 21], 1u);
    }
  }
  __syncthreads();

  // parallel threshold search: thread t owns buckets [8t, 8t+8)
  unsigned int hm[8];
#pragma unroll
  for (int i = 0; i < 8; ++i) hm[i] = 0u;
#pragma unroll
  for (int w = 0; w < 4; ++w) {
    uint4 p0 = *(const uint4*)&hist4[w][tid * 8];
    uint4 p1 = *(const uint4*)&hist4[w][tid * 8 + 4];
    hm[0] += p0.x; hm[1] += p0.y; hm[2] += p0.z; hm[3] += p0.w;
    hm[4] += p1.x; hm[5] += p1.y; hm[6] += p1.z; hm[7] += p1.w;
  }
  unsigned int sc = hm[0] + hm[1] + hm[2] + hm[3] + hm[4] + hm[5] + hm[6] + hm[7];
  csum[tid] = sc;
  __syncthreads();
  for (int off = 1; off < 256; off <<= 1) {
    unsigned int v_ = (tid + off < 256) ? csum[tid + off] : 0u;
    __syncthreads();
    csum[tid] += v_;
    __syncthreads();
  }
  {
    unsigned int above = (tid < 255) ? csum[tid + 1] : 0u;
    if (csum[tid] >= K_N && above < K_N) {
      unsigned int run = above;
      int T = 0;
#pragma unroll
      for (int i = 7; i >= 0; --i) {
        run += hm[i];
        if (run >= K_N) { T = tid * 8 + i; break; }
      }
      s_T = T;
    }
  }
  __syncthreads();
  int T = s_T;

  // pass 2: collect definite (bucket > T) and candidates (bucket == T)
  for (int j = 0; j < E_N / 1024; ++j) {
    int i4 = tid + j * 256;
    float4 v = ((const float4*)row)[i4];
    float f[4] = {v.x, v.y, v.z, v.w};
#pragma unroll
    for (int q = 0; q < 4; ++q) {
      float vv = f[q];
      unsigned int u = __float_as_uint(vv);
      unsigned int key = (u & 0x80000000u) ? ~u : (u | 0x80000000u);
      int bk = key >> 21;
      if (bk > T) {
        int d = atomicAdd(&s_nDef, 1);
        defV[d] = vv;
        defI[d] = i4 * 4 + q;
      } else if (bk == T) {
        int c = atomicAdd(&s_nCand, 1);
        candV[c] = vv;
        candI[c] = i4 * 4 + q;
      }
    }
  }
  __syncthreads();
  int nDef = s_nDef;
  int nCand = s_nCand;
  int need = K_N - nDef;

  if (tid < nDef) {
    topk_idx[b * K_N + tid] = defI[tid];
    topk_val[b * K_N + tid] = defV[tid];
    live_p[defI[tid]] = 1;
  }
  for (int c = tid; c < nCand; c += 256) {
    float v = candV[c];
    int idx = candI[c];
    int r = 0;
    for (int j2 = 0; j2 < nCand; ++j2) {
      float vj = candV[j2];
      r += (vj > v) || (vj == v && candI[j2] < idx);
    }
    if (r < need) {
      int slot = nDef + r;
      topk_idx[b * K_N + slot] = idx;
      topk_val[b * K_N + slot] = v;
      live_p[idx] = 1;
    }
  }
}

// ---------------------------------------------------------------------------
// Fused child + recon per row b, v3.
// Phase 1: 2 slots/wave iteration; lane0 writes only cs/wf/liveness.
// Phase 1.5: stats gathers + cos for all 32 slots in PARALLEL (tid<32),
// replacing 8x-serialized lane0 chains. Phase 2: branchless, unroll 4.
// ---------------------------------------------------------------------------
__global__ __launch_bounds__(256, 6) void child_recon_kernel(
    const float* __restrict__ x, const float* __restrict__ e1w, const float* __restrict__ e1b,
    const float* __restrict__ e2w, const float* __restrict__ e2b,
    const int* __restrict__ topk_idx, const float* __restrict__ topk_val,
    int* __restrict__ live_c1, int* __restrict__ live_c2,
    const float* __restrict__ stats, float* __restrict__ aux_sum,
    const float* __restrict__ decT0, const float* __restrict__ decT1,
    const float* __restrict__ decT2,
    const float* __restrict__ db0, const float* __restrict__ db1,
    const float* __restrict__ db2, float* __restrict__ out) {
  int b = blockIdx.x;
  int tid = threadIdx.x;
  int lane = tid & 63;
  int wave = tid >> 6;

  __shared__ float xs[M_N];
  __shared__ int es[K_N];
  __shared__ float as[K_N], cs[K_N];
  __shared__ int wf[K_N];

  if (tid < K_N) {
    es[tid] = topk_idx[b * K_N + tid];
    as[tid] = topk_val[b * K_N + tid];
  }
  if (tid < M_N / 4) ((float4*)xs)[tid] = ((const float4*)(x + (size_t)b * M_N))[tid];
  __syncthreads();

#pragma unroll
  for (int it = 0; it < 4; ++it) {
    int sA = it * 8 + wave * 2;
    int sB = sA + 1;
    int eA = es[sA], eB = es[sB];
    float aA = as[sA], aB = as[sB];
    const float* w1A = e1w + (size_t)eA * M_N;
    const float* w2A = e2w + (size_t)eA * M_N;
    const float* w1B = e1w + (size_t)eB * M_N;
    const float* w2B = e2w + (size_t)eB * M_N;
    float d1A = 0.f, d2A = 0.f, d1B = 0.f, d2B = 0.f;
#pragma unroll
    for (int j = 0; j < 3; ++j) {
      int m = (lane << 2) + j * 256;
      float4 xv = *(const float4*)&xs[m];
      float4 a1 = *(const float4*)&w1A[m];
      float4 a2 = *(const float4*)&w2A[m];
      float4 b1 = *(const float4*)&w1B[m];
      float4 b2 = *(const float4*)&w2B[m];
      d1A += xv.x * a1.x + xv.y * a1.y + xv.z * a1.z + xv.w * a1.w;
      d2A += xv.x * a2.x + xv.y * a2.y + xv.z * a2.z + xv.w * a2.w;
      d1B += xv.x * b1.x + xv.y * b1.y + xv.z * b1.z + xv.w * b1.w;
      d2B += xv.x * b2.x + xv.y * b2.y + xv.z * b2.z + xv.w * b2.w;
    }
#pragma unroll
    for (int off = 32; off > 0; off >>= 1) {
      d1A += __shfl_down(d1A, off);
      d2A += __shfl_down(d2A, off);
      d1B += __shfl_down(d1B, off);
      d2B += __shfl_down(d2B, off);
    }
    if (lane == 0) {
#pragma unroll
      for (int h = 0; h < 2; ++h) {
        int s = h ? sB : sA;
        int e = h ? eB : eA;
        float a = h ? aB : aA;
        float d1 = h ? d1B : d1A;
        float d2 = h ? d2B : d2A;
        if (a != 0.f) {
          float m1 = d1 + e1b[e];
          float m2 = d2 + e2b[e];
          bool win = m1 > m2;
          float f1 = win ? m1 : 0.f;
          float f2 = win ? 0.f : m2;
          float c = win ? f1 : f2;
          cs[s] = c;
          wf[s] = win ? 1 : 0;
          if (f1 != 0.f) live_c1[e] = 1;
          if (f2 != 0.f) live_c2[e] = 1;
        } else {
          cs[s] = 0.f;
          wf[s] = 0;
        }
      }
    }
  }
  __syncthreads();

  // phase 1.5: parallel stats gather + cos for all slots, reduce in wave 0
  float cosv = 0.f;
  if (tid < K_N) {
    float a = as[tid];
    if (a > 0.f) {
      int e = es[tid];
      float c = cs[tid];
      int win = wf[tid];
      float np2e = stats[e];
      float nce = win ? stats[E_N + e] : stats[2 * E_N + e];
      float dpc = win ? stats[3 * E_N + e] : stats[4 * E_N + e];
      float a2 = a * a;
      float dot = a2 * np2e + a * c * dpc;
      float normp = fabsf(a) * sqrtf(np2e);
      float comb2 = a2 * np2e + 2.f * a * c * dpc + c * c * nce;
      float normc = sqrtf(fmaxf(comb2, 0.f));
      cosv = dot / (fmaxf(normp, EPSF) * fmaxf(normc, EPSF));
    }
  }
  if (tid < 64) {
#pragma unroll
    for (int off = 32; off > 0; off >>= 1) cosv += __shfl_down(cosv, off);
    if (tid == 0) atomicAdd(aux_sum, cosv);
  }

  // phase 2: recon — branchless, deep unroll for MLP
  float acc0 = db0[tid] + db1[tid] + db2[tid];
  float acc1 = db0[tid + 256] + db1[tid + 256] + db2[tid + 256];
  float acc2 = db0[tid + 512] + db1[tid + 512] + db2[tid + 512];

#pragma unroll 4
  for (int s = 0; s < K_N; ++s) {
    int e = es[s];
    float a = as[s];
    float c = cs[s];
    const float* p = decT0 + (size_t)e * M_N;
    const float* q = (wf[s] ? decT1 : decT2) + (size_t)e * M_N;
    float p0 = p[tid], p1 = p[tid + 256], p2 = p[tid + 512];
    float q0 = q[tid], q1 = q[tid + 256], q2 = q[tid + 512];
    acc0 = fmaf(a, p0, fmaf(c, q0, acc0));
    acc1 = fmaf(a, p1, fmaf(c, q1, acc1));
    acc2 = fmaf(a, p2, fmaf(c, q2, acc2));
  }
  out[(size_t)b * M_N + tid] = acc0;
  out[(size_t)b * M_N + tid + 256] = acc1;
  out[(size_t)b * M_N + tid + 512] = acc2;
}

// ---------------------------------------------------------------------------
__global__ void finalize_kernel(const int* __restrict__ live_p, const int* __restrict__ live_c1,
                                const int* __restrict__ live_c2, const float* __restrict__ aux_sum,
                                float* __restrict__ out_tail) {
  int tid = threadIdx.x;
  int c0 = 0, c1 = 0, c2 = 0;
  for (int i = tid; i < E_N; i += 256) {
    c0 += live_p[i];
    c1 += live_c1[i];
    c2 += live_c2[i];
  }
  __shared__ int r0[256], r1[256], r2[256];
  r0[tid] = c0; r1[tid] = c1; r2[tid] = c2;
  __syncthreads();
  for (int s = 128; s > 0; s >>= 1) {
    if (tid < s) { r0[tid] += r0[tid + s]; r1[tid] += r1[tid + s]; r2[tid] += r2[tid + s]; }
    __syncthreads();
  }
  if (tid == 0) {
    out_tail[0] = (float)r0[0];
    out_tail[1] = (float)r1[0];
    out_tail[2] = (float)r2[0];
    out_tail[3] = -aux_sum[0] / (float)B_N;
  }
}

// ---------------------------------------------------------------------------
// Workspace:
//   Big region (reused): phase 1 [pre], phase 2 [decT0..2]
//   Tail: [stats 5E | livep E | livec1 E | livec2 E | aux 1] (zeroed once)
//         [tidx | tval]
// ---------------------------------------------------------------------------
extern "C" void kernel_launch(void* const* d_in, const int* in_sizes, int n_in,
                              void* d_out, int out_size, void* d_ws, size_t ws_size,
                              hipStream_t stream) {
  const float* x     = (const float*)d_in[0];
  const float* enc_w = (const float*)d_in[1];
  const float* enc_b = (const float*)d_in[2];
  const float* dec_w = (const float*)d_in[3];
  const float* dec_b = (const float*)d_in[4];
  const float* e1w   = (const float*)d_in[5];
  const float* e1b   = (const float*)d_in[6];
  const float* d1w   = (const float*)d_in[7];
  const float* d1b   = (const float*)d_in[8];
  const float* e2w   = (const float*)d_in[9];
  const float* e2b   = (const float*)d_in[10];
  const float* d2w   = (const float*)d_in[11];
  const float* d2b   = (const float*)d_in[12];

  float* wsf = (float*)d_ws;

  const size_t PRE_F = (size_t)B_N * E_N;       // 33.5M floats
  const size_t DEC_F = (size_t)E_N * M_N;       // 12.6M floats
  const size_t BIG_F = (PRE_F > 3 * DEC_F) ? PRE_F : 3 * DEC_F;

  float* pre = wsf;
  float* decT0 = wsf;
  float* decT1 = wsf + DEC_F;
  float* decT2 = wsf + 2 * DEC_F;

  size_t off = BIG_F;
  float* stats  = wsf + off;
  int*   livep  = (int*)(wsf + off + 5 * (size_t)E_N);
  int*   livec1 = livep + E_N;
  int*   livec2 = livep + 2 * E_N;
  float* auxs   = (float*)(livep + 3 * E_N);
  off += 8 * (size_t)E_N + 64;
  off &= ~(size_t)63;
  int*   tidx = (int*)(wsf + off);    off += (size_t)B_N * K_N;
  float* tval = wsf + off;            off += (size_t)B_N * K_N;

  // zero stats + live flags + aux in one shot
  hipMemsetAsync(stats, 0, (8 * (size_t)E_N + 1) * sizeof(float), stream);

  // phase 1: gemm (fused f32->split-bf16 staging) -> topk
  const int HB = B_N / 2;
  gemm_mfma_kernel<<<dim3(E_N / TN, HB / TM), 256, 0, stream>>>(x, enc_w, enc_b, pre);
  gemm_mfma_kernel<<<dim3(E_N / TN, HB / TM), 256, 0, stream>>>(
      x + (size_t)HB * M_N, enc_w, enc_b, pre + (size_t)HB * E_N);

  topk_kernel<<<B_N, 256, 0, stream>>>(pre, tidx, tval, livep);

  // phase 2: fused decoder prep (overwrites big region), then fused child+recon
  prep_dec_kernel<<<dim3(E_N / 32, M_N / 32), 256, 0, stream>>>(
      dec_w, d1w, d2w, decT0, decT1, decT2, stats);

  float* out = (float*)d_out;
  child_recon_kernel<<<B_N, 256, 0, stream>>>(x, e1w, e1b, e2w, e2b, tidx, tval,
                                              livec1, livec2, stats, auxs,
                                              decT0, decT1, decT2, dec_b, d1b, d2b, out);

  finalize_kernel<<<1, 256, 0, stream>>>(livep, livec1, livec2, auxs,
                                         out + (size_t)B_N * M_N);
}

// Round 5
// 654.799 us; speedup vs baseline: 1.0331x; 1.0331x over previous
//
#include <hip/hip_runtime.h>
#include <cstdint>
#include <cstddef>

#define B_N 2048
#define M_N 768
#define E_N 16384
#define K_N 32
#define EPSF 1e-8f

typedef __attribute__((ext_vector_type(8))) short short8;
typedef __attribute__((ext_vector_type(4))) float floatx4;
typedef __attribute__((ext_vector_type(4))) unsigned short ushort4v;

__device__ inline unsigned short f2bf(float f) {
  unsigned int u = __float_as_uint(f);
  unsigned int r = (u + 0x7fffu + ((u >> 16) & 1u)) >> 16;
  return (unsigned short)r;
}
__device__ inline float bf2f(unsigned short h) {
  return __uint_as_float(((unsigned int)h) << 16);
}

// ---------------------------------------------------------------------------
// Fused split for both inputs: f32 -> (hi, lo) bf16 pair.
// (Measured best: amortizes conversion once; fusing into GEMM staging
//  regressed MfmaUtil 39->26% by lengthening the staging critical path.)
// ---------------------------------------------------------------------------
__global__ __launch_bounds__(256) void split2_kernel(
    const float* __restrict__ inA, unsigned short* __restrict__ hiA,
    unsigned short* __restrict__ loA, int n4A,
    const float* __restrict__ inB, unsigned short* __restrict__ hiB,
    unsigned short* __restrict__ loB, int n4B) {
  int i = blockIdx.x * 256 + threadIdx.x;
  const float* in;
  unsigned short* hi;
  unsigned short* lo;
  int idx;
  if (i < n4A) {
    in = inA; hi = hiA; lo = loA; idx = i;
  } else {
    idx = i - n4A;
    if (idx >= n4B) return;
    in = inB; hi = hiB; lo = loB;
  }
  float4 v = ((const float4*)in)[idx];
  ushort4v h, l;
  h.x = f2bf(v.x); l.x = f2bf(v.x - bf2f(h.x));
  h.y = f2bf(v.y); l.y = f2bf(v.y - bf2f(h.y));
  h.z = f2bf(v.z); l.z = f2bf(v.z - bf2f(h.z));
  h.w = f2bf(v.w); l.w = f2bf(v.w - bf2f(h.w));
  ((ushort4v*)hi)[idx] = h;
  ((ushort4v*)lo)[idx] = l;
}

// ---------------------------------------------------------------------------
// Fused decoder prep: float4 global loads AND float4 global stores.
// Transpose all three [M,E]->[E,M] + accumulate 5 per-column stats from the
// LDS tiles during the store phase. stats pre-zeroed. grid (E/32, M/32).
// ---------------------------------------------------------------------------
__global__ __launch_bounds__(256) void prep_dec_kernel(
    const float* __restrict__ dw, const float* __restrict__ d1,
    const float* __restrict__ d2,
    float* __restrict__ dT0, float* __restrict__ dT1,
    float* __restrict__ dT2, float* __restrict__ stats) {
  __shared__ float t0[32][36], t1[32][36], t2[32][36];
  int tid = threadIdx.x;
  int e0 = blockIdx.x * 32;
  int m0 = blockIdx.y * 32;

  {
    int ml = tid >> 3, e4 = tid & 7;
    size_t gbase = (size_t)(m0 + ml) * E_N + e0 + e4 * 4;
    float4 a  = *(const float4*)&dw[gbase];
    float4 b1 = *(const float4*)&d1[gbase];
    float4 b2 = *(const float4*)&d2[gbase];
    *(float4*)&t0[ml][e4 * 4] = a;
    *(float4*)&t1[ml][e4 * 4] = b1;
    *(float4*)&t2[ml][e4 * 4] = b2;
  }
  __syncthreads();

  int el = tid >> 3, m4 = tid & 7;
  float4 v0, v1, v2;
  float s0 = 0.f, s1 = 0.f, s2 = 0.f, s3 = 0.f, s4 = 0.f;
#pragma unroll
  for (int j = 0; j < 4; ++j) {
    float A  = t0[m4 * 4 + j][el];
    float B1 = t1[m4 * 4 + j][el];
    float B2 = t2[m4 * 4 + j][el];
    ((float*)&v0)[j] = A;
    ((float*)&v1)[j] = B1;
    ((float*)&v2)[j] = B2;
    s0 = fmaf(A, A, s0);
    s1 = fmaf(B1, B1, s1);
    s2 = fmaf(B2, B2, s2);
    s3 = fmaf(A, B1, s3);
    s4 = fmaf(A, B2, s4);
  }
  size_t tbase = (size_t)(e0 + el) * M_N + m0 + m4 * 4;
  *(float4*)&dT0[tbase] = v0;
  *(float4*)&dT1[tbase] = v1;
  *(float4*)&dT2[tbase] = v2;

#pragma unroll
  for (int off = 1; off < 8; off <<= 1) {
    s0 += __shfl_xor(s0, off);
    s1 += __shfl_xor(s1, off);
    s2 += __shfl_xor(s2, off);
    s3 += __shfl_xor(s3, off);
    s4 += __shfl_xor(s4, off);
  }
  if (m4 == 0) {
    int e = e0 + el;
    atomicAdd(&stats[e], s0);
    atomicAdd(&stats[E_N + e], s1);
    atomicAdd(&stats[2 * E_N + e], s2);
    atomicAdd(&stats[3 * E_N + e], s3);
    atomicAdd(&stats[4 * E_N + e], s4);
  }
}

// ---------------------------------------------------------------------------
// pre = x @ enc_w.T + enc_b  via split-bf16 MFMA (hi*hi + hi*lo + lo*hi).
// ---------------------------------------------------------------------------
#define TM 128
#define TN 128
#define TK 32
#define LDK 40

__global__ __launch_bounds__(256) void gemm_mfma_kernel(
    const unsigned short* __restrict__ Ahi, const unsigned short* __restrict__ Alo,
    const unsigned short* __restrict__ Bhi, const unsigned short* __restrict__ Blo,
    const float* __restrict__ bias, float* __restrict__ C) {
  __shared__ __align__(16) unsigned short As_hi[TM * LDK];
  __shared__ __align__(16) unsigned short As_lo[TM * LDK];
  __shared__ __align__(16) unsigned short Bs_hi[TM * LDK];
  __shared__ __align__(16) unsigned short Bs_lo[TM * LDK];

  int tid = threadIdx.x;
  int lane = tid & 63;
  int wave = tid >> 6;
  int i0 = blockIdx.y * TM;
  int j0 = blockIdx.x * TN;
  int wm = (wave >> 1) * 64;
  int wn = (wave & 1) * 64;

  int row0 = tid >> 2, c40 = tid & 3;
  int row1 = 64 + (tid >> 2), c41 = tid & 3;
  const unsigned short* pAhi0 = Ahi + (size_t)(i0 + row0) * M_N + c40 * 8;
  const unsigned short* pAhi1 = Ahi + (size_t)(i0 + row1) * M_N + c41 * 8;
  const unsigned short* pAlo0 = Alo + (size_t)(i0 + row0) * M_N + c40 * 8;
  const unsigned short* pAlo1 = Alo + (size_t)(i0 + row1) * M_N + c41 * 8;
  const unsigned short* pBhi0 = Bhi + (size_t)(j0 + row0) * M_N + c40 * 8;
  const unsigned short* pBhi1 = Bhi + (size_t)(j0 + row1) * M_N + c41 * 8;
  const unsigned short* pBlo0 = Blo + (size_t)(j0 + row0) * M_N + c40 * 8;
  const unsigned short* pBlo1 = Blo + (size_t)(j0 + row1) * M_N + c41 * 8;
  int l0 = row0 * LDK + c40 * 8;
  int l1 = row1 * LDK + c41 * 8;

  floatx4 acc[4][4];
#pragma unroll
  for (int i = 0; i < 4; ++i)
#pragma unroll
    for (int j = 0; j < 4; ++j) acc[i][j] = (floatx4){0.f, 0.f, 0.f, 0.f};

  int fr = lane & 15;
  int fk = (lane >> 4) * 8;

  short8 vAh0 = *(const short8*)pAhi0;
  short8 vAh1 = *(const short8*)pAhi1;
  short8 vAl0 = *(const short8*)pAlo0;
  short8 vAl1 = *(const short8*)pAlo1;
  short8 vBh0 = *(const short8*)pBhi0;
  short8 vBh1 = *(const short8*)pBhi1;
  short8 vBl0 = *(const short8*)pBlo0;
  short8 vBl1 = *(const short8*)pBlo1;

  for (int k0 = 0; k0 < M_N; k0 += TK) {
    __syncthreads();
    *(short8*)&As_hi[l0] = vAh0;
    *(short8*)&As_hi[l1] = vAh1;
    *(short8*)&As_lo[l0] = vAl0;
    *(short8*)&As_lo[l1] = vAl1;
    *(short8*)&Bs_hi[l0] = vBh0;
    *(short8*)&Bs_hi[l1] = vBh1;
    *(short8*)&Bs_lo[l0] = vBl0;
    *(short8*)&Bs_lo[l1] = vBl1;
    __syncthreads();

    if (k0 + TK < M_N) {
      int d = k0 + TK;
      vAh0 = *(const short8*)(pAhi0 + d);
      vAh1 = *(const short8*)(pAhi1 + d);
      vAl0 = *(const short8*)(pAlo0 + d);
      vAl1 = *(const short8*)(pAlo1 + d);
      vBh0 = *(const short8*)(pBhi0 + d);
      vBh1 = *(const short8*)(pBhi1 + d);
      vBl0 = *(const short8*)(pBlo0 + d);
      vBl1 = *(const short8*)(pBlo1 + d);
    }

    short8 ah[4], al[4], bh[4], bl[4];
#pragma unroll
    for (int t = 0; t < 4; ++t) {
      int ar = (wm + t * 16 + fr) * LDK + fk;
      int br = (wn + t * 16 + fr) * LDK + fk;
      ah[t] = *(const short8*)&As_hi[ar];
      al[t] = *(const short8*)&As_lo[ar];
      bh[t] = *(const short8*)&Bs_hi[br];
      bl[t] = *(const short8*)&Bs_lo[br];
    }
#pragma unroll
    for (int mi = 0; mi < 4; ++mi)
#pragma unroll
      for (int ni = 0; ni < 4; ++ni) {
        acc[mi][ni] = __builtin_amdgcn_mfma_f32_16x16x32_bf16(ah[mi], bh[ni], acc[mi][ni], 0, 0, 0);
        acc[mi][ni] = __builtin_amdgcn_mfma_f32_16x16x32_bf16(ah[mi], bl[ni], acc[mi][ni], 0, 0, 0);
        acc[mi][ni] = __builtin_amdgcn_mfma_f32_16x16x32_bf16(al[mi], bh[ni], acc[mi][ni], 0, 0, 0);
      }
  }

#pragma unroll
  for (int mi = 0; mi < 4; ++mi) {
    int rbase = i0 + wm + mi * 16 + (lane >> 4) * 4;
#pragma unroll
    for (int ni = 0; ni < 4; ++ni) {
      int col = j0 + wn + ni * 16 + (lane & 15);
      float bb = bias[col];
#pragma unroll
      for (int r = 0; r < 4; ++r) {
        C[(size_t)(rbase + r) * E_N + col] = acc[mi][ni][r] + bb;
      }
    }
  }
}

// ---------------------------------------------------------------------------
// Exact top-K per row via radix-select on the monotone u32 key.
// Matches jax.lax.top_k (ties -> lowest index).
// ---------------------------------------------------------------------------
__global__ __launch_bounds__(256) void topk_kernel(const float* __restrict__ pre,
                                                   int* __restrict__ topk_idx,
                                                   float* __restrict__ topk_val,
                                                   int* __restrict__ live_p) {
  int b = blockIdx.x;
  int tid = threadIdx.x;
  int wave = tid >> 6;
  const float* row = pre + (size_t)b * E_N;

  __shared__ __align__(16) unsigned int hist4[4][2048];  // 32 KB
  __shared__ unsigned int csum[256];
  __shared__ float candV[2048];
  __shared__ int candI[2048];
  __shared__ float defV[K_N];
  __shared__ int defI[K_N];
  __shared__ int s_T, s_nDef, s_nCand;

  uint4 z4 = make_uint4(0u, 0u, 0u, 0u);
  uint4* hz = (uint4*)&hist4[0][0];
  for (int i = tid; i < 2048; i += 256) hz[i] = z4;
  if (tid == 0) { s_nDef = 0; s_nCand = 0; }
  __syncthreads();

  // pass 1: per-wave histogram of top-11 key bits (float4 loads)
  for (int j = 0; j < E_N / 1024; ++j) {
    float4 v = ((const float4*)row)[tid + j * 256];
    float f[4] = {v.x, v.y, v.z, v.w};
#pragma unroll
    for (int q = 0; q < 4; ++q) {
      unsigned int u = __float_as_uint(f[q]);
      unsigned int key = (u & 0x80000000u) ? ~u : (u | 0x80000000u);
      atomicAdd(&hist4[wave][key >> 21], 1u);
    }
  }
  __syncthreads();

  // parallel threshold search: thread t owns buckets [8t, 8t+8)
  unsigned int hm[8];
#pragma unroll
  for (int i = 0; i < 8; ++i) hm[i] = 0u;
#pragma unroll
  for (int w = 0; w < 4; ++w) {
    uint4 p0 = *(const uint4*)&hist4[w][tid * 8];
    uint4 p1 = *(const uint4*)&hist4[w][tid * 8 + 4];
    hm[0] += p0.x; hm[1] += p0.y; hm[2] += p0.z; hm[3] += p0.w;
    hm[4] += p1.x; hm[5] += p1.y; hm[6] += p1.z; hm[7] += p1.w;
  }
  unsigned int sc = hm[0] + hm[1] + hm[2] + hm[3] + hm[4] + hm[5] + hm[6] + hm[7];
  csum[tid] = sc;
  __syncthreads();
  for (int off = 1; off < 256; off <<= 1) {
    unsigned int v_ = (tid + off < 256) ? csum[tid + off] : 0u;
    __syncthreads();
    csum[tid] += v_;
    __syncthreads();
  }
  {
    unsigned int above = (tid < 255) ? csum[tid + 1] : 0u;
    if (csum[tid] >= K_N && above < K_N) {
      unsigned int run = above;
      int T = 0;
#pragma unroll
      for (int i = 7; i >= 0; --i) {
        run += hm[i];
        if (run >= K_N) { T = tid * 8 + i; break; }
      }
      s_T = T;
    }
  }
  __syncthreads();
  int T = s_T;

  // pass 2: collect definite (bucket > T) and candidates (bucket == T)
  for (int j = 0; j < E_N / 1024; ++j) {
    int i4 = tid + j * 256;
    float4 v = ((const float4*)row)[i4];
    float f[4] = {v.x, v.y, v.z, v.w};
#pragma unroll
    for (int q = 0; q < 4; ++q) {
      float vv = f[q];
      unsigned int u = __float_as_uint(vv);
      unsigned int key = (u & 0x80000000u) ? ~u : (u | 0x80000000u);
      int bk = key >> 21;
      if (bk > T) {
        int d = atomicAdd(&s_nDef, 1);
        defV[d] = vv;
        defI[d] = i4 * 4 + q;
      } else if (bk == T) {
        int c = atomicAdd(&s_nCand, 1);
        candV[c] = vv;
        candI[c] = i4 * 4 + q;
      }
    }
  }
  __syncthreads();
  int nDef = s_nDef;
  int nCand = s_nCand;
  int need = K_N - nDef;

  if (tid < nDef) {
    topk_idx[b * K_N + tid] = defI[tid];
    topk_val[b * K_N + tid] = defV[tid];
    live_p[defI[tid]] = 1;
  }
  for (int c = tid; c < nCand; c += 256) {
    float v = candV[c];
    int idx = candI[c];
    int r = 0;
    for (int j2 = 0; j2 < nCand; ++j2) {
      float vj = candV[j2];
      r += (vj > v) || (vj == v && candI[j2] < idx);
    }
    if (r < need) {
      int slot = nDef + r;
      topk_idx[b * K_N + slot] = idx;
      topk_val[b * K_N + slot] = v;
      live_p[idx] = 1;
    }
  }
}

// ---------------------------------------------------------------------------
// Fused child + recon per row, v3. blockIdx.x = local b; pointers pre-offset
// per half-B dispatch (rows independent; split only for rocprof visibility).
// ---------------------------------------------------------------------------
__global__ __launch_bounds__(256, 6) void child_recon_kernel(
    const float* __restrict__ x, const float* __restrict__ e1w, const float* __restrict__ e1b,
    const float* __restrict__ e2w, const float* __restrict__ e2b,
    const int* __restrict__ topk_idx, const float* __restrict__ topk_val,
    int* __restrict__ live_c1, int* __restrict__ live_c2,
    const float* __restrict__ stats, float* __restrict__ aux_sum,
    const float* __restrict__ decT0, const float* __restrict__ decT1,
    const float* __restrict__ decT2,
    const float* __restrict__ db0, const float* __restrict__ db1,
    const float* __restrict__ db2, float* __restrict__ out) {
  int b = blockIdx.x;
  int tid = threadIdx.x;
  int lane = tid & 63;
  int wave = tid >> 6;

  __shared__ float xs[M_N];
  __shared__ int es[K_N];
  __shared__ float as[K_N], cs[K_N];
  __shared__ int wf[K_N];

  if (tid < K_N) {
    es[tid] = topk_idx[b * K_N + tid];
    as[tid] = topk_val[b * K_N + tid];
  }
  if (tid < M_N / 4) ((float4*)xs)[tid] = ((const float4*)(x + (size_t)b * M_N))[tid];
  __syncthreads();

#pragma unroll
  for (int it = 0; it < 4; ++it) {
    int sA = it * 8 + wave * 2;
    int sB = sA + 1;
    int eA = es[sA], eB = es[sB];
    float aA = as[sA], aB = as[sB];
    const float* w1A = e1w + (size_t)eA * M_N;
    const float* w2A = e2w + (size_t)eA * M_N;
    const float* w1B = e1w + (size_t)eB * M_N;
    const float* w2B = e2w + (size_t)eB * M_N;
    float d1A = 0.f, d2A = 0.f, d1B = 0.f, d2B = 0.f;
#pragma unroll
    for (int j = 0; j < 3; ++j) {
      int m = (lane << 2) + j * 256;
      float4 xv = *(const float4*)&xs[m];
      float4 a1 = *(const float4*)&w1A[m];
      float4 a2 = *(const float4*)&w2A[m];
      float4 b1 = *(const float4*)&w1B[m];
      float4 b2 = *(const float4*)&w2B[m];
      d1A += xv.x * a1.x + xv.y * a1.y + xv.z * a1.z + xv.w * a1.w;
      d2A += xv.x * a2.x + xv.y * a2.y + xv.z * a2.z + xv.w * a2.w;
      d1B += xv.x * b1.x + xv.y * b1.y + xv.z * b1.z + xv.w * b1.w;
      d2B += xv.x * b2.x + xv.y * b2.y + xv.z * b2.z + xv.w * b2.w;
    }
#pragma unroll
    for (int off = 32; off > 0; off >>= 1) {
      d1A += __shfl_down(d1A, off);
      d2A += __shfl_down(d2A, off);
      d1B += __shfl_down(d1B, off);
      d2B += __shfl_down(d2B, off);
    }
    if (lane == 0) {
#pragma unroll
      for (int h = 0; h < 2; ++h) {
        int s = h ? sB : sA;
        int e = h ? eB : eA;
        float a = h ? aB : aA;
        float d1 = h ? d1B : d1A;
        float d2 = h ? d2B : d2A;
        if (a != 0.f) {
          float m1 = d1 + e1b[e];
          float m2 = d2 + e2b[e];
          bool win = m1 > m2;
          float f1 = win ? m1 : 0.f;
          float f2 = win ? 0.f : m2;
          float c = win ? f1 : f2;
          cs[s] = c;
          wf[s] = win ? 1 : 0;
          if (f1 != 0.f) live_c1[e] = 1;
          if (f2 != 0.f) live_c2[e] = 1;
        } else {
          cs[s] = 0.f;
          wf[s] = 0;
        }
      }
    }
  }
  __syncthreads();

  // phase 1.5: parallel stats gather + cos for all slots, reduce in wave 0
  float cosv = 0.f;
  if (tid < K_N) {
    float a = as[tid];
    if (a > 0.f) {
      int e = es[tid];
      float c = cs[tid];
      int win = wf[tid];
      float np2e = stats[e];
      float nce = win ? stats[E_N + e] : stats[2 * E_N + e];
      float dpc = win ? stats[3 * E_N + e] : stats[4 * E_N + e];
      float a2 = a * a;
      float dot = a2 * np2e + a * c * dpc;
      float normp = fabsf(a) * sqrtf(np2e);
      float comb2 = a2 * np2e + 2.f * a * c * dpc + c * c * nce;
      float normc = sqrtf(fmaxf(comb2, 0.f));
      cosv = dot / (fmaxf(normp, EPSF) * fmaxf(normc, EPSF));
    }
  }
  if (tid < 64) {
#pragma unroll
    for (int off = 32; off > 0; off >>= 1) cosv += __shfl_down(cosv, off);
    if (tid == 0) atomicAdd(aux_sum, cosv);
  }

  // phase 2: recon — branchless, deep unroll for MLP
  float acc0 = db0[tid] + db1[tid] + db2[tid];
  float acc1 = db0[tid + 256] + db1[tid + 256] + db2[tid + 256];
  float acc2 = db0[tid + 512] + db1[tid + 512] + db2[tid + 512];

#pragma unroll 4
  for (int s = 0; s < K_N; ++s) {
    int e = es[s];
    float a = as[s];
    float c = cs[s];
    const float* p = decT0 + (size_t)e * M_N;
    const float* q = (wf[s] ? decT1 : decT2) + (size_t)e * M_N;
    float p0 = p[tid], p1 = p[tid + 256], p2 = p[tid + 512];
    float q0 = q[tid], q1 = q[tid + 256], q2 = q[tid + 512];
    acc0 = fmaf(a, p0, fmaf(c, q0, acc0));
    acc1 = fmaf(a, p1, fmaf(c, q1, acc1));
    acc2 = fmaf(a, p2, fmaf(c, q2, acc2));
  }
  out[(size_t)b * M_N + tid] = acc0;
  out[(size_t)b * M_N + tid + 256] = acc1;
  out[(size_t)b * M_N + tid + 512] = acc2;
}

// ---------------------------------------------------------------------------
__global__ void finalize_kernel(const int* __restrict__ live_p, const int* __restrict__ live_c1,
                                const int* __restrict__ live_c2, const float* __restrict__ aux_sum,
                                float* __restrict__ out_tail) {
  int tid = threadIdx.x;
  int c0 = 0, c1 = 0, c2 = 0;
  for (int i = tid; i < E_N; i += 256) {
    c0 += live_p[i];
    c1 += live_c1[i];
    c2 += live_c2[i];
  }
  __shared__ int r0[256], r1[256], r2[256];
  r0[tid] = c0; r1[tid] = c1; r2[tid] = c2;
  __syncthreads();
  for (int s = 128; s > 0; s >>= 1) {
    if (tid < s) { r0[tid] += r0[tid + s]; r1[tid] += r1[tid + s]; r2[tid] += r2[tid + s]; }
    __syncthreads();
  }
  if (tid == 0) {
    out_tail[0] = (float)r0[0];
    out_tail[1] = (float)r1[0];
    out_tail[2] = (float)r2[0];
    out_tail[3] = -aux_sum[0] / (float)B_N;
  }
}

// ---------------------------------------------------------------------------
// Workspace (all offsets multiples of 64 floats):
//   Big region (reused): phase 1 [pre | xhi xlo | ewhi ewlo], phase 2 [decT0..2]
//   Tail: [stats 5E | livep E | livec1 E | livec2 E | aux 1]  (zeroed once)
//         [tidx | tval]
// ---------------------------------------------------------------------------
extern "C" void kernel_launch(void* const* d_in, const int* in_sizes, int n_in,
                              void* d_out, int out_size, void* d_ws, size_t ws_size,
                              hipStream_t stream) {
  const float* x     = (const float*)d_in[0];
  const float* enc_w = (const float*)d_in[1];
  const float* enc_b = (const float*)d_in[2];
  const float* dec_w = (const float*)d_in[3];
  const float* dec_b = (const float*)d_in[4];
  const float* e1w   = (const float*)d_in[5];
  const float* e1b   = (const float*)d_in[6];
  const float* d1w   = (const float*)d_in[7];
  const float* d1b   = (const float*)d_in[8];
  const float* e2w   = (const float*)d_in[9];
  const float* e2b   = (const float*)d_in[10];
  const float* d2w   = (const float*)d_in[11];
  const float* d2b   = (const float*)d_in[12];

  float* wsf = (float*)d_ws;

  const size_t PRE_F = (size_t)B_N * E_N;
  const size_t XSP_F = (size_t)B_N * M_N / 2;
  const size_t ESP_F = (size_t)E_N * M_N / 2;
  const size_t DEC_F = (size_t)E_N * M_N;
  const size_t BIG_F = PRE_F + 2 * XSP_F + 2 * ESP_F;

  float* pre = wsf;
  unsigned short* xhi  = (unsigned short*)(wsf + PRE_F);
  unsigned short* xlo  = (unsigned short*)(wsf + PRE_F + XSP_F);
  unsigned short* ewhi = (unsigned short*)(wsf + PRE_F + 2 * XSP_F);
  unsigned short* ewlo = (unsigned short*)(wsf + PRE_F + 2 * XSP_F + ESP_F);
  float* decT0 = wsf;
  float* decT1 = wsf + DEC_F;
  float* decT2 = wsf + 2 * DEC_F;

  size_t off = BIG_F;
  float* stats  = wsf + off;
  int*   livep  = (int*)(wsf + off + 5 * (size_t)E_N);
  int*   livec1 = livep + E_N;
  int*   livec2 = livep + 2 * E_N;
  float* auxs   = (float*)(livep + 3 * E_N);
  off += 8 * (size_t)E_N + 64;
  off &= ~(size_t)63;
  int*   tidx = (int*)(wsf + off);    off += (size_t)B_N * K_N;
  float* tval = wsf + off;            off += (size_t)B_N * K_N;

  // zero stats + live flags + aux in one shot
  hipMemsetAsync(stats, 0, (8 * (size_t)E_N + 1) * sizeof(float), stream);

  // phase 1: split -> gemm -> topk
  int n4A = B_N * M_N / 4;
  int n4B = E_N * M_N / 4;
  split2_kernel<<<(n4A + n4B + 255) / 256, 256, 0, stream>>>(x, xhi, xlo, n4A,
                                                             enc_w, ewhi, ewlo, n4B);

  const int HB = B_N / 2;
  gemm_mfma_kernel<<<dim3(E_N / TN, HB / TM), 256, 0, stream>>>(xhi, xlo, ewhi, ewlo, enc_b, pre);
  gemm_mfma_kernel<<<dim3(E_N / TN, HB / TM), 256, 0, stream>>>(
      xhi + (size_t)HB * M_N, xlo + (size_t)HB * M_N, ewhi, ewlo, enc_b,
      pre + (size_t)HB * E_N);

  topk_kernel<<<B_N, 256, 0, stream>>>(pre, tidx, tval, livep);

  // phase 2: fused decoder prep (overwrites big region), then fused child+recon
  prep_dec_kernel<<<dim3(E_N / 32, M_N / 32), 256, 0, stream>>>(
      dec_w, d1w, d2w, decT0, decT1, decT2, stats);

  float* out = (float*)d_out;
  child_recon_kernel<<<HB, 256, 0, stream>>>(x, e1w, e1b, e2w, e2b, tidx, tval,
                                             livec1, livec2, stats, auxs,
                                             decT0, decT1, decT2, dec_b, d1b, d2b, out);
  child_recon_kernel<<<HB, 256, 0, stream>>>(
      x + (size_t)HB * M_N, e1w, e1b, e2w, e2b, tidx + (size_t)HB * K_N,
      tval + (size_t)HB * K_N, livec1, livec2, stats, auxs,
      decT0, decT1, decT2, dec_b, d1b, d2b, out + (size_t)HB * M_N);

  finalize_kernel<<<1, 256, 0, stream>>>(livep, livec1, livec2, auxs,
                                         out + (size_t)B_N * M_N);
}

// Round 6
// 613.763 us; speedup vs baseline: 1.1022x; 1.0669x over previous
//
#include <hip/hip_runtime.h>
#include <cstdint>
#include <cstddef>

#define B_N 2048
#define M_N 768
#define E_N 16384
#define K_N 32
#define EPSF 1e-8f

typedef __attribute__((ext_vector_type(8))) short short8;
typedef __attribute__((ext_vector_type(4))) float floatx4;
typedef __attribute__((ext_vector_type(4))) unsigned short ushort4v;

__device__ inline unsigned short f2bf(float f) {
  unsigned int u = __float_as_uint(f);
  unsigned int r = (u + 0x7fffu + ((u >> 16) & 1u)) >> 16;
  return (unsigned short)r;
}
__device__ inline float bf2f(unsigned short h) {
  return __uint_as_float(((unsigned int)h) << 16);
}

// ---------------------------------------------------------------------------
// Fused split for both inputs: f32 -> (hi, lo) bf16 pair.
// (Measured best: amortizes conversion once; fusing into GEMM staging
//  regressed MfmaUtil 39->26% by lengthening the staging critical path.)
// ---------------------------------------------------------------------------
__global__ __launch_bounds__(256) void split2_kernel(
    const float* __restrict__ inA, unsigned short* __restrict__ hiA,
    unsigned short* __restrict__ loA, int n4A,
    const float* __restrict__ inB, unsigned short* __restrict__ hiB,
    unsigned short* __restrict__ loB, int n4B) {
  int i = blockIdx.x * 256 + threadIdx.x;
  const float* in;
  unsigned short* hi;
  unsigned short* lo;
  int idx;
  if (i < n4A) {
    in = inA; hi = hiA; lo = loA; idx = i;
  } else {
    idx = i - n4A;
    if (idx >= n4B) return;
    in = inB; hi = hiB; lo = loB;
  }
  float4 v = ((const float4*)in)[idx];
  ushort4v h, l;
  h.x = f2bf(v.x); l.x = f2bf(v.x - bf2f(h.x));
  h.y = f2bf(v.y); l.y = f2bf(v.y - bf2f(h.y));
  h.z = f2bf(v.z); l.z = f2bf(v.z - bf2f(h.z));
  h.w = f2bf(v.w); l.w = f2bf(v.w - bf2f(h.w));
  ((ushort4v*)hi)[idx] = h;
  ((ushort4v*)lo)[idx] = l;
}

// ---------------------------------------------------------------------------
// Fused decoder prep v3: 64x64 tiles (4x fewer blocks, 4x fewer barriers,
// half the atomics, deeper per-thread MLP). float4 on both global sides.
// grid (E/64, M/64), block 256. stats pre-zeroed.
// ---------------------------------------------------------------------------
__global__ __launch_bounds__(256) void prep_dec_kernel(
    const float* __restrict__ dw, const float* __restrict__ d1,
    const float* __restrict__ d2,
    float* __restrict__ dT0, float* __restrict__ dT1,
    float* __restrict__ dT2, float* __restrict__ stats) {
  __shared__ float t0[64][68], t1[64][68], t2[64][68];  // 52.2 KB
  int tid = threadIdx.x;
  int e0 = blockIdx.x * 64;
  int m0 = blockIdx.y * 64;

  // load: 16 rows/iteration, 256B contiguous per row
  int ml = tid >> 4, e4 = tid & 15;
#pragma unroll
  for (int r = 0; r < 64; r += 16) {
    size_t g = (size_t)(m0 + ml + r) * E_N + e0 + e4 * 4;
    *(float4*)&t0[ml + r][e4 * 4] = *(const float4*)&dw[g];
    *(float4*)&t1[ml + r][e4 * 4] = *(const float4*)&d1[g];
    *(float4*)&t2[ml + r][e4 * 4] = *(const float4*)&d2[g];
  }
  __syncthreads();

  // store: thread (elb, m4) covers e = elb + 32*ee, m = m4*4 + jj*32 + j
  // 8 lanes x 16B = 128B contiguous per e-row segment.
  int m4 = tid & 7;
  int elb = tid >> 3;  // 0..31
#pragma unroll
  for (int ee = 0; ee < 2; ++ee) {
    int el = elb + ee * 32;
    float s0 = 0.f, s1 = 0.f, s2 = 0.f, s3 = 0.f, s4 = 0.f;
#pragma unroll
    for (int jj = 0; jj < 2; ++jj) {
      float4 v0, v1, v2;
#pragma unroll
      for (int j = 0; j < 4; ++j) {
        int m = m4 * 4 + jj * 32 + j;
        float A  = t0[m][el];
        float B1 = t1[m][el];
        float B2 = t2[m][el];
        ((float*)&v0)[j] = A;
        ((float*)&v1)[j] = B1;
        ((float*)&v2)[j] = B2;
        s0 = fmaf(A, A, s0);
        s1 = fmaf(B1, B1, s1);
        s2 = fmaf(B2, B2, s2);
        s3 = fmaf(A, B1, s3);
        s4 = fmaf(A, B2, s4);
      }
      size_t tb = (size_t)(e0 + el) * M_N + m0 + m4 * 4 + jj * 32;
      *(float4*)&dT0[tb] = v0;
      *(float4*)&dT1[tb] = v1;
      *(float4*)&dT2[tb] = v2;
    }
#pragma unroll
    for (int off = 1; off < 8; off <<= 1) {
      s0 += __shfl_xor(s0, off);
      s1 += __shfl_xor(s1, off);
      s2 += __shfl_xor(s2, off);
      s3 += __shfl_xor(s3, off);
      s4 += __shfl_xor(s4, off);
    }
    if (m4 == 0) {
      int e = e0 + el;
      atomicAdd(&stats[e], s0);
      atomicAdd(&stats[E_N + e], s1);
      atomicAdd(&stats[2 * E_N + e], s2);
      atomicAdd(&stats[3 * E_N + e], s3);
      atomicAdd(&stats[4 * E_N + e], s4);
    }
  }
}

// ---------------------------------------------------------------------------
// pre = x @ enc_w.T + enc_b  via split-bf16 MFMA (hi*hi + hi*lo + lo*hi).
// Single full-B dispatch (measured 174.8us; half-splits cost +16us in tails).
// ---------------------------------------------------------------------------
#define TM 128
#define TN 128
#define TK 32
#define LDK 40

__global__ __launch_bounds__(256) void gemm_mfma_kernel(
    const unsigned short* __restrict__ Ahi, const unsigned short* __restrict__ Alo,
    const unsigned short* __restrict__ Bhi, const unsigned short* __restrict__ Blo,
    const float* __restrict__ bias, float* __restrict__ C) {
  __shared__ __align__(16) unsigned short As_hi[TM * LDK];
  __shared__ __align__(16) unsigned short As_lo[TM * LDK];
  __shared__ __align__(16) unsigned short Bs_hi[TM * LDK];
  __shared__ __align__(16) unsigned short Bs_lo[TM * LDK];

  int tid = threadIdx.x;
  int lane = tid & 63;
  int wave = tid >> 6;
  int i0 = blockIdx.y * TM;
  int j0 = blockIdx.x * TN;
  int wm = (wave >> 1) * 64;
  int wn = (wave & 1) * 64;

  int row0 = tid >> 2, c40 = tid & 3;
  int row1 = 64 + (tid >> 2), c41 = tid & 3;
  const unsigned short* pAhi0 = Ahi + (size_t)(i0 + row0) * M_N + c40 * 8;
  const unsigned short* pAhi1 = Ahi + (size_t)(i0 + row1) * M_N + c41 * 8;
  const unsigned short* pAlo0 = Alo + (size_t)(i0 + row0) * M_N + c40 * 8;
  const unsigned short* pAlo1 = Alo + (size_t)(i0 + row1) * M_N + c41 * 8;
  const unsigned short* pBhi0 = Bhi + (size_t)(j0 + row0) * M_N + c40 * 8;
  const unsigned short* pBhi1 = Bhi + (size_t)(j0 + row1) * M_N + c41 * 8;
  const unsigned short* pBlo0 = Blo + (size_t)(j0 + row0) * M_N + c40 * 8;
  const unsigned short* pBlo1 = Blo + (size_t)(j0 + row1) * M_N + c41 * 8;
  int l0 = row0 * LDK + c40 * 8;
  int l1 = row1 * LDK + c41 * 8;

  floatx4 acc[4][4];
#pragma unroll
  for (int i = 0; i < 4; ++i)
#pragma unroll
    for (int j = 0; j < 4; ++j) acc[i][j] = (floatx4){0.f, 0.f, 0.f, 0.f};

  int fr = lane & 15;
  int fk = (lane >> 4) * 8;

  short8 vAh0 = *(const short8*)pAhi0;
  short8 vAh1 = *(const short8*)pAhi1;
  short8 vAl0 = *(const short8*)pAlo0;
  short8 vAl1 = *(const short8*)pAlo1;
  short8 vBh0 = *(const short8*)pBhi0;
  short8 vBh1 = *(const short8*)pBhi1;
  short8 vBl0 = *(const short8*)pBlo0;
  short8 vBl1 = *(const short8*)pBlo1;

  for (int k0 = 0; k0 < M_N; k0 += TK) {
    __syncthreads();
    *(short8*)&As_hi[l0] = vAh0;
    *(short8*)&As_hi[l1] = vAh1;
    *(short8*)&As_lo[l0] = vAl0;
    *(short8*)&As_lo[l1] = vAl1;
    *(short8*)&Bs_hi[l0] = vBh0;
    *(short8*)&Bs_hi[l1] = vBh1;
    *(short8*)&Bs_lo[l0] = vBl0;
    *(short8*)&Bs_lo[l1] = vBl1;
    __syncthreads();

    if (k0 + TK < M_N) {
      int d = k0 + TK;
      vAh0 = *(const short8*)(pAhi0 + d);
      vAh1 = *(const short8*)(pAhi1 + d);
      vAl0 = *(const short8*)(pAlo0 + d);
      vAl1 = *(const short8*)(pAlo1 + d);
      vBh0 = *(const short8*)(pBhi0 + d);
      vBh1 = *(const short8*)(pBhi1 + d);
      vBl0 = *(const short8*)(pBlo0 + d);
      vBl1 = *(const short8*)(pBlo1 + d);
    }

    short8 ah[4], al[4], bh[4], bl[4];
#pragma unroll
    for (int t = 0; t < 4; ++t) {
      int ar = (wm + t * 16 + fr) * LDK + fk;
      int br = (wn + t * 16 + fr) * LDK + fk;
      ah[t] = *(const short8*)&As_hi[ar];
      al[t] = *(const short8*)&As_lo[ar];
      bh[t] = *(const short8*)&Bs_hi[br];
      bl[t] = *(const short8*)&Bs_lo[br];
    }
#pragma unroll
    for (int mi = 0; mi < 4; ++mi)
#pragma unroll
      for (int ni = 0; ni < 4; ++ni) {
        acc[mi][ni] = __builtin_amdgcn_mfma_f32_16x16x32_bf16(ah[mi], bh[ni], acc[mi][ni], 0, 0, 0);
        acc[mi][ni] = __builtin_amdgcn_mfma_f32_16x16x32_bf16(ah[mi], bl[ni], acc[mi][ni], 0, 0, 0);
        acc[mi][ni] = __builtin_amdgcn_mfma_f32_16x16x32_bf16(al[mi], bh[ni], acc[mi][ni], 0, 0, 0);
      }
  }

#pragma unroll
  for (int mi = 0; mi < 4; ++mi) {
    int rbase = i0 + wm + mi * 16 + (lane >> 4) * 4;
#pragma unroll
    for (int ni = 0; ni < 4; ++ni) {
      int col = j0 + wn + ni * 16 + (lane & 15);
      float bb = bias[col];
#pragma unroll
      for (int r = 0; r < 4; ++r) {
        C[(size_t)(rbase + r) * E_N + col] = acc[mi][ni][r] + bb;
      }
    }
  }
}

// ---------------------------------------------------------------------------
// Exact top-K per row via radix-select on the monotone u32 key.
// v3: row values register-resident (64 VGPRs, fully-unrolled constant
// indexing) -> ONE global read instead of two; pass 2 runs from registers.
// Matches jax.lax.top_k (ties -> lowest index).
// ---------------------------------------------------------------------------
__global__ __launch_bounds__(256) void topk_kernel(const float* __restrict__ pre,
                                                   int* __restrict__ topk_idx,
                                                   float* __restrict__ topk_val,
                                                   int* __restrict__ live_p) {
  int b = blockIdx.x;
  int tid = threadIdx.x;
  int wave = tid >> 6;
  const float* row = pre + (size_t)b * E_N;

  __shared__ __align__(16) unsigned int hist4[4][2048];  // 32 KB
  __shared__ unsigned int csum[256];
  __shared__ float candV[2048];
  __shared__ int candI[2048];
  __shared__ float defV[K_N];
  __shared__ int defI[K_N];
  __shared__ int s_T, s_nDef, s_nCand;

  uint4 z4 = make_uint4(0u, 0u, 0u, 0u);
  uint4* hz = (uint4*)&hist4[0][0];
  for (int i = tid; i < 2048; i += 256) hz[i] = z4;
  if (tid == 0) { s_nDef = 0; s_nCand = 0; }
  __syncthreads();

  // single global read: row values -> registers
  float rv[64];
#pragma unroll
  for (int j = 0; j < 16; ++j) {
    float4 v = ((const float4*)row)[tid + j * 256];
    rv[4 * j + 0] = v.x;
    rv[4 * j + 1] = v.y;
    rv[4 * j + 2] = v.z;
    rv[4 * j + 3] = v.w;
  }

  // pass 1: per-wave histogram of top-11 key bits (from registers)
#pragma unroll
  for (int j = 0; j < 64; ++j) {
    unsigned int u = __float_as_uint(rv[j]);
    unsigned int key = (u & 0x80000000u) ? ~u : (u | 0x80000000u);
    atomicAdd(&hist4[wave][key >> 21], 1u);
  }
  __syncthreads();

  // parallel threshold search: thread t owns buckets [8t, 8t+8)
  unsigned int hm[8];
#pragma unroll
  for (int i = 0; i < 8; ++i) hm[i] = 0u;
#pragma unroll
  for (int w = 0; w < 4; ++w) {
    uint4 p0 = *(const uint4*)&hist4[w][tid * 8];
    uint4 p1 = *(const uint4*)&hist4[w][tid * 8 + 4];
    hm[0] += p0.x; hm[1] += p0.y; hm[2] += p0.z; hm[3] += p0.w;
    hm[4] += p1.x; hm[5] += p1.y; hm[6] += p1.z; hm[7] += p1.w;
  }
  unsigned int sc = hm[0] + hm[1] + hm[2] + hm[3] + hm[4] + hm[5] + hm[6] + hm[7];
  csum[tid] = sc;
  __syncthreads();
  // Hillis-Steele inclusive suffix scan over 256 chunks
  for (int off = 1; off < 256; off <<= 1) {
    unsigned int v_ = (tid + off < 256) ? csum[tid + off] : 0u;
    __syncthreads();
    csum[tid] += v_;
    __syncthreads();
  }
  {
    unsigned int above = (tid < 255) ? csum[tid + 1] : 0u;
    if (csum[tid] >= K_N && above < K_N) {
      unsigned int run = above;
      int T = 0;
#pragma unroll
      for (int i = 7; i >= 0; --i) {
        run += hm[i];
        if (run >= K_N) { T = tid * 8 + i; break; }
      }
      s_T = T;
    }
  }
  __syncthreads();
  int T = s_T;

  // pass 2: collect definite (bucket > T) and candidates (bucket == T)
  // from the register copy — no second global read.
#pragma unroll
  for (int jj = 0; jj < 64; ++jj) {
    float vv = rv[jj];
    unsigned int u = __float_as_uint(vv);
    unsigned int key = (u & 0x80000000u) ? ~u : (u | 0x80000000u);
    int bk = key >> 21;
    if (bk >= T) {
      int idx = (tid + (jj >> 2) * 256) * 4 + (jj & 3);
      if (bk > T) {
        int d = atomicAdd(&s_nDef, 1);
        defV[d] = vv;
        defI[d] = idx;
      } else {
        int c = atomicAdd(&s_nCand, 1);
        candV[c] = vv;
        candI[c] = idx;
      }
    }
  }
  __syncthreads();
  int nDef = s_nDef;        // < K_N by construction
  int nCand = s_nCand;
  int need = K_N - nDef;

  if (tid < nDef) {
    topk_idx[b * K_N + tid] = defI[tid];
    topk_val[b * K_N + tid] = defV[tid];
    live_p[defI[tid]] = 1;
  }
  // rank candidates by (value desc, index asc); rank < need -> selected
  for (int c = tid; c < nCand; c += 256) {
    float v = candV[c];
    int idx = candI[c];
    int r = 0;
    for (int j2 = 0; j2 < nCand; ++j2) {
      float vj = candV[j2];
      r += (vj > v) || (vj == v && candI[j2] < idx);
    }
    if (r < need) {
      int slot = nDef + r;
      topk_idx[b * K_N + slot] = idx;
      topk_val[b * K_N + slot] = v;
      live_p[idx] = 1;
    }
  }
}

// ---------------------------------------------------------------------------
// Fused child + recon per row b, v3 (single full-B dispatch).
// Phase 1: 2 slots/wave iteration. Phase 1.5: parallel stats+cos (tid<32).
// Phase 2: branchless recon, unroll 4.
// ---------------------------------------------------------------------------
__global__ __launch_bounds__(256, 6) void child_recon_kernel(
    const float* __restrict__ x, const float* __restrict__ e1w, const float* __restrict__ e1b,
    const float* __restrict__ e2w, const float* __restrict__ e2b,
    const int* __restrict__ topk_idx, const float* __restrict__ topk_val,
    int* __restrict__ live_c1, int* __restrict__ live_c2,
    const float* __restrict__ stats, float* __restrict__ aux_sum,
    const float* __restrict__ decT0, const float* __restrict__ decT1,
    const float* __restrict__ decT2,
    const float* __restrict__ db0, const float* __restrict__ db1,
    const float* __restrict__ db2, float* __restrict__ out) {
  int b = blockIdx.x;
  int tid = threadIdx.x;
  int lane = tid & 63;
  int wave = tid >> 6;

  __shared__ float xs[M_N];
  __shared__ int es[K_N];
  __shared__ float as[K_N], cs[K_N];
  __shared__ int wf[K_N];

  if (tid < K_N) {
    es[tid] = topk_idx[b * K_N + tid];
    as[tid] = topk_val[b * K_N + tid];
  }
  if (tid < M_N / 4) ((float4*)xs)[tid] = ((const float4*)(x + (size_t)b * M_N))[tid];
  __syncthreads();

#pragma unroll
  for (int it = 0; it < 4; ++it) {
    int sA = it * 8 + wave * 2;
    int sB = sA + 1;
    int eA = es[sA], eB = es[sB];
    float aA = as[sA], aB = as[sB];
    const float* w1A = e1w + (size_t)eA * M_N;
    const float* w2A = e2w + (size_t)eA * M_N;
    const float* w1B = e1w + (size_t)eB * M_N;
    const float* w2B = e2w + (size_t)eB * M_N;
    float d1A = 0.f, d2A = 0.f, d1B = 0.f, d2B = 0.f;
#pragma unroll
    for (int j = 0; j < 3; ++j) {
      int m = (lane << 2) + j * 256;
      float4 xv = *(const float4*)&xs[m];
      float4 a1 = *(const float4*)&w1A[m];
      float4 a2 = *(const float4*)&w2A[m];
      float4 b1 = *(const float4*)&w1B[m];
      float4 b2 = *(const float4*)&w2B[m];
      d1A += xv.x * a1.x + xv.y * a1.y + xv.z * a1.z + xv.w * a1.w;
      d2A += xv.x * a2.x + xv.y * a2.y + xv.z * a2.z + xv.w * a2.w;
      d1B += xv.x * b1.x + xv.y * b1.y + xv.z * b1.z + xv.w * b1.w;
      d2B += xv.x * b2.x + xv.y * b2.y + xv.z * b2.z + xv.w * b2.w;
    }
#pragma unroll
    for (int off = 32; off > 0; off >>= 1) {
      d1A += __shfl_down(d1A, off);
      d2A += __shfl_down(d2A, off);
      d1B += __shfl_down(d1B, off);
      d2B += __shfl_down(d2B, off);
    }
    if (lane == 0) {
#pragma unroll
      for (int h = 0; h < 2; ++h) {
        int s = h ? sB : sA;
        int e = h ? eB : eA;
        float a = h ? aB : aA;
        float d1 = h ? d1B : d1A;
        float d2 = h ? d2B : d2A;
        if (a != 0.f) {
          float m1 = d1 + e1b[e];
          float m2 = d2 + e2b[e];
          bool win = m1 > m2;
          float f1 = win ? m1 : 0.f;
          float f2 = win ? 0.f : m2;
          float c = win ? f1 : f2;
          cs[s] = c;
          wf[s] = win ? 1 : 0;
          if (f1 != 0.f) live_c1[e] = 1;
          if (f2 != 0.f) live_c2[e] = 1;
        } else {
          cs[s] = 0.f;
          wf[s] = 0;
        }
      }
    }
  }
  __syncthreads();

  // phase 1.5: parallel stats gather + cos for all slots, reduce in wave 0
  float cosv = 0.f;
  if (tid < K_N) {
    float a = as[tid];
    if (a > 0.f) {
      int e = es[tid];
      float c = cs[tid];
      int win = wf[tid];
      float np2e = stats[e];
      float nce = win ? stats[E_N + e] : stats[2 * E_N + e];
      float dpc = win ? stats[3 * E_N + e] : stats[4 * E_N + e];
      float a2 = a * a;
      float dot = a2 * np2e + a * c * dpc;
      float normp = fabsf(a) * sqrtf(np2e);
      float comb2 = a2 * np2e + 2.f * a * c * dpc + c * c * nce;
      float normc = sqrtf(fmaxf(comb2, 0.f));
      cosv = dot / (fmaxf(normp, EPSF) * fmaxf(normc, EPSF));
    }
  }
  if (tid < 64) {
#pragma unroll
    for (int off = 32; off > 0; off >>= 1) cosv += __shfl_down(cosv, off);
    if (tid == 0) atomicAdd(aux_sum, cosv);
  }

  // phase 2: recon — branchless, deep unroll for MLP
  float acc0 = db0[tid] + db1[tid] + db2[tid];
  float acc1 = db0[tid + 256] + db1[tid + 256] + db2[tid + 256];
  float acc2 = db0[tid + 512] + db1[tid + 512] + db2[tid + 512];

#pragma unroll 4
  for (int s = 0; s < K_N; ++s) {
    int e = es[s];
    float a = as[s];
    float c = cs[s];
    const float* p = decT0 + (size_t)e * M_N;
    const float* q = (wf[s] ? decT1 : decT2) + (size_t)e * M_N;
    float p0 = p[tid], p1 = p[tid + 256], p2 = p[tid + 512];
    float q0 = q[tid], q1 = q[tid + 256], q2 = q[tid + 512];
    acc0 = fmaf(a, p0, fmaf(c, q0, acc0));
    acc1 = fmaf(a, p1, fmaf(c, q1, acc1));
    acc2 = fmaf(a, p2, fmaf(c, q2, acc2));
  }
  out[(size_t)b * M_N + tid] = acc0;
  out[(size_t)b * M_N + tid + 256] = acc1;
  out[(size_t)b * M_N + tid + 512] = acc2;
}

// ---------------------------------------------------------------------------
__global__ void finalize_kernel(const int* __restrict__ live_p, const int* __restrict__ live_c1,
                                const int* __restrict__ live_c2, const float* __restrict__ aux_sum,
                                float* __restrict__ out_tail) {
  int tid = threadIdx.x;
  int c0 = 0, c1 = 0, c2 = 0;
  for (int i = tid; i < E_N; i += 256) {
    c0 += live_p[i];
    c1 += live_c1[i];
    c2 += live_c2[i];
  }
  __shared__ int r0[256], r1[256], r2[256];
  r0[tid] = c0; r1[tid] = c1; r2[tid] = c2;
  __syncthreads();
  for (int s = 128; s > 0; s >>= 1) {
    if (tid < s) { r0[tid] += r0[tid + s]; r1[tid] += r1[tid + s]; r2[tid] += r2[tid + s]; }
    __syncthreads();
  }
  if (tid == 0) {
    out_tail[0] = (float)r0[0];
    out_tail[1] = (float)r1[0];
    out_tail[2] = (float)r2[0];
    out_tail[3] = -aux_sum[0] / (float)B_N;
  }
}

// ---------------------------------------------------------------------------
// Workspace (all offsets multiples of 64 floats):
//   Big region (reused): phase 1 [pre | xhi xlo | ewhi ewlo], phase 2 [decT0..2]
//   Tail: [stats 5E | livep E | livec1 E | livec2 E | aux 1]  (zeroed once)
//         [tidx | tval]
// ---------------------------------------------------------------------------
extern "C" void kernel_launch(void* const* d_in, const int* in_sizes, int n_in,
                              void* d_out, int out_size, void* d_ws, size_t ws_size,
                              hipStream_t stream) {
  const float* x     = (const float*)d_in[0];
  const float* enc_w = (const float*)d_in[1];
  const float* enc_b = (const float*)d_in[2];
  const float* dec_w = (const float*)d_in[3];
  const float* dec_b = (const float*)d_in[4];
  const float* e1w   = (const float*)d_in[5];
  const float* e1b   = (const float*)d_in[6];
  const float* d1w   = (const float*)d_in[7];
  const float* d1b   = (const float*)d_in[8];
  const float* e2w   = (const float*)d_in[9];
  const float* e2b   = (const float*)d_in[10];
  const float* d2w   = (const float*)d_in[11];
  const float* d2b   = (const float*)d_in[12];

  float* wsf = (float*)d_ws;

  const size_t PRE_F = (size_t)B_N * E_N;
  const size_t XSP_F = (size_t)B_N * M_N / 2;
  const size_t ESP_F = (size_t)E_N * M_N / 2;
  const size_t DEC_F = (size_t)E_N * M_N;
  const size_t BIG_F = PRE_F + 2 * XSP_F + 2 * ESP_F;

  float* pre = wsf;
  unsigned short* xhi  = (unsigned short*)(wsf + PRE_F);
  unsigned short* xlo  = (unsigned short*)(wsf + PRE_F + XSP_F);
  unsigned short* ewhi = (unsigned short*)(wsf + PRE_F + 2 * XSP_F);
  unsigned short* ewlo = (unsigned short*)(wsf + PRE_F + 2 * XSP_F + ESP_F);
  float* decT0 = wsf;
  float* decT1 = wsf + DEC_F;
  float* decT2 = wsf + 2 * DEC_F;

  size_t off = BIG_F;
  float* stats  = wsf + off;
  int*   livep  = (int*)(wsf + off + 5 * (size_t)E_N);
  int*   livec1 = livep + E_N;
  int*   livec2 = livep + 2 * E_N;
  float* auxs   = (float*)(livep + 3 * E_N);
  off += 8 * (size_t)E_N + 64;
  off &= ~(size_t)63;
  int*   tidx = (int*)(wsf + off);    off += (size_t)B_N * K_N;
  float* tval = wsf + off;            off += (size_t)B_N * K_N;

  // zero stats + live flags + aux in one shot
  hipMemsetAsync(stats, 0, (8 * (size_t)E_N + 1) * sizeof(float), stream);

  // phase 1: split -> gemm (single dispatch) -> topk
  int n4A = B_N * M_N / 4;
  int n4B = E_N * M_N / 4;
  split2_kernel<<<(n4A + n4B + 255) / 256, 256, 0, stream>>>(x, xhi, xlo, n4A,
                                                             enc_w, ewhi, ewlo, n4B);

  gemm_mfma_kernel<<<dim3(E_N / TN, B_N / TM), 256, 0, stream>>>(xhi, xlo, ewhi, ewlo, enc_b, pre);

  topk_kernel<<<B_N, 256, 0, stream>>>(pre, tidx, tval, livep);

  // phase 2: fused decoder prep (overwrites big region), then fused child+recon
  prep_dec_kernel<<<dim3(E_N / 64, M_N / 64), 256, 0, stream>>>(
      dec_w, d1w, d2w, decT0, decT1, decT2, stats);

  float* out = (float*)d_out;
  child_recon_kernel<<<B_N, 256, 0, stream>>>(x, e1w, e1b, e2w, e2b, tidx, tval,
                                              livec1, livec2, stats, auxs,
                                              decT0, decT1, decT2, dec_b, d1b, d2b, out);

  finalize_kernel<<<1, 256, 0, stream>>>(livep, livec1, livec2, auxs,
                                         out + (size_t)B_N * M_N);
}